// Round 1
// baseline (143.609 us; speedup 1.0000x reference)
//
#include <hip/hip_runtime.h>
#include <hip/hip_fp16.h>

// Ultimus: out = x + softmax((x@Kw+Kb)@(x@Qw+Qb)^T / sqrt(8)) @ (x@Vw+Vb) @ Zw + Zb
// N=8192, D_IN=48, D_ATTN=8, fp32 in/out.
//
// R12 = R11 with ONE structural change in attn: the per-pair QV stream moves
// off the scalar-memory path (s_load_dwordx16, which forces lgkmcnt(0) full
// drains because SMEM returns out-of-order, and thrashes the small sL1 with
// 8 blocks/CU x 16KB slabs) onto the VECTOR path: the pair base is pinned
// into a VGPR via opaque asm, so loads become global_load_dwordx4 with all
// lanes at the same address -> coalesced to one L1 transaction + broadcast,
// vmcnt-pipelined ~16 deep under unroll 4. Math is bit-identical to R11.
// Also: finish_kernel 64 -> 256 blocks (32 rows each) so its latency-bound
// part-reduction uses all 256 CUs.
//
//  - Bound-softmax (Cauchy-Schwarz row bound) => fixed per-row exponent
//    shift; partials over disjoint j-chunks combine by pure addition.
//  - QV pair-interleaved: dword c of pair p = half2(val[2p][c], val[2p+1][c])
//    so one pk_fma accumulates scores for both j's of the pair at once.
//
// ws layout (floats):
//   [0, 32768)      Xksf16[8192] 8 f16/row (k * log2e/sqrt(8)), uint4/row
//   [32768, 98304)  QV per pair p: 16 dwords = q2pair[8] | v2pair[8]
//   [98304, 98560)  bmax[256] per-proj-block max ||q||^2 (plain store)
//   [98560, ...)    part[nch][8192][9] f32 partials: acc[0:8], l at [8]

#define QV_OFF   32768
#define BMAX_OFF 98304
#define PART_OFF 98560

typedef _Float16 hv2 __attribute__((ext_vector_type(2)));
union HVU { unsigned u; hv2 v; };

static __device__ __forceinline__ unsigned pku(float a, float b) {
    auto t = __builtin_amdgcn_cvt_pkrtz(a, b);
    union { decltype(t) x; unsigned u; } c; c.x = t; return c.u;
}
static __device__ __forceinline__ hv2 asV(unsigned u) { HVU t; t.u = u; return t.v; }
static __device__ __forceinline__ hv2 h2fma(hv2 a, hv2 b, hv2 c) {
#if __has_builtin(__builtin_elementwise_fma)
    return __builtin_elementwise_fma(a, b, c);
#else
    union { hv2 v; __half2 h; } A, B, C, D;
    A.v = a; B.v = b; C.v = c;
    D.h = __hfma2(A.h, B.h, C.h);
    return D.v;
#endif
}
static __device__ __forceinline__ unsigned dupL(unsigned u) {
    const unsigned lo = u & 0xFFFFu; return lo | (lo << 16);
}
static __device__ __forceinline__ unsigned dupH(unsigned u) {
    const unsigned hi = u >> 16; return hi | (hi << 16);
}

__global__ __launch_bounds__(256) void proj_kernel(
    const float* __restrict__ x,
    const float* __restrict__ Kw, const float* __restrict__ Kb,
    const float* __restrict__ Qw, const float* __restrict__ Qb,
    const float* __restrict__ Vw, const float* __restrict__ Vb,
    unsigned* __restrict__ Xksf16, unsigned* __restrict__ QV,
    float* __restrict__ bmax)
{
    __shared__ float xs[32 * 49];     // +1 pad
    __shared__ float wAll[3 * 388];   // stride 388 (mod 32 = 4) spreads 3 mats
    __shared__ float bs[24];
    __shared__ float outv[32][25];    // 24 cols + pad
    const int tid = threadIdx.x;
    const int r0 = blockIdx.x * 32;

    for (int i = tid; i < 1536; i += 256) {
        int r = i / 48, c = i - r * 48;
        xs[r * 49 + c] = x[r0 * 48 + i];
    }
    for (int i = tid; i < 384; i += 256) {
        wAll[i]       = Kw[i];
        wAll[388 + i] = Qw[i];
        wAll[776 + i] = Vw[i];
    }
    if (tid < 8)       bs[tid] = Kb[tid];
    else if (tid < 16) bs[tid] = Qb[tid - 8];
    else if (tid < 24) bs[tid] = Vb[tid - 16];
    __syncthreads();

    const int rl = tid >> 3;
    const int g  = tid & 7;
    const int c0 = 3 * g;
    const float* xr = &xs[rl * 49];
    const float* w0 = &wAll[((c0 + 0) >> 3) * 388 + ((c0 + 0) & 7)];
    const float* w1 = &wAll[((c0 + 1) >> 3) * 388 + ((c0 + 1) & 7)];
    const float* w2 = &wAll[((c0 + 2) >> 3) * 388 + ((c0 + 2) & 7)];
    float a0 = bs[c0], a1 = bs[c0 + 1], a2 = bs[c0 + 2];
    #pragma unroll
    for (int k = 0; k < 48; k++) {
        const float xv = xr[k];
        a0 = fmaf(xv, w0[k * 8], a0);
        a1 = fmaf(xv, w1[k * 8], a1);
        a2 = fmaf(xv, w2[k * 8], a2);
    }
    outv[rl][c0] = a0; outv[rl][c0 + 1] = a1; outv[rl][c0 + 2] = a2;
    __syncthreads();

    // QV pair-interleaved: pair p (16/block), col c (8), m: 0=q, 1=v
    {
        const int p = tid >> 4;
        const int c = (tid >> 1) & 7;
        const int m = tid & 1;
        const int col = (m ? 16 : 8) + c;
        QV[(blockIdx.x * 16 + p) * 16 + m * 8 + c] =
            pku(outv[2 * p][col], outv[2 * p + 1][col]);
    }
    const float kscale = 0.51008732149f;  // (1/sqrt(8)) * log2(e)
    if (tid < 32) {                       // K rows, f16 packed, pre-scaled
        uint4 o;
        o.x = pku(outv[tid][0] * kscale, outv[tid][1] * kscale);
        o.y = pku(outv[tid][2] * kscale, outv[tid][3] * kscale);
        o.z = pku(outv[tid][4] * kscale, outv[tid][5] * kscale);
        o.w = pku(outv[tid][6] * kscale, outv[tid][7] * kscale);
        ((uint4*)Xksf16)[r0 + tid] = o;
    }
    if (tid >= 192 && tid < 224) {        // block-max ||q||^2 (fp32)
        const int r = tid - 192;
        float n2 = 0.f;
        #pragma unroll
        for (int c = 0; c < 8; c++) n2 = fmaf(outv[r][8 + c], outv[r][8 + c], n2);
        #pragma unroll
        for (int off = 16; off > 0; off >>= 1)
            n2 = fmaxf(n2, __shfl_xor(n2, off, 64));
        if (r == 0) bmax[blockIdx.x] = n2;
    }
}

// grid = 128 row-groups (64 rows; row = lane) x nch j-chunks.
// Wave w handles pairs [(chunk*4 + w)*ppw, +ppw). The pair base is pinned
// into a VGPR (opaque asm) so QV loads take the VECTOR path:
// global_load_dwordx4, all lanes same addr -> one L1 transaction, broadcast,
// vmcnt-pipelined. (R11 used s_load_dwordx16: SMEM returns out-of-order ->
// lgkmcnt(0) full drain per unroll group + sL1 thrash across 8 blocks/CU.)
__global__ __launch_bounds__(256) void attn_kernel(
    const unsigned* __restrict__ Xksf16, const unsigned* __restrict__ QV,
    const float* __restrict__ bmax,
    float* __restrict__ part, int ppw)
{
    __shared__ float red[4][64][13];   // stride 13: conflict-light
    const int tid  = threadIdx.x;
    const int lane = tid & 63;
    const int wv   = tid >> 6;
    const int rgrp  = blockIdx.x & 127;
    const int chunk = blockIdx.x >> 7;
    const int row   = rgrp * 64 + lane;

    // qmax2 = max over 256 per-proj-block maxima
    float m = fmaxf(fmaxf(bmax[lane], bmax[64 + lane]),
                    fmaxf(bmax[128 + lane], bmax[192 + lane]));
    #pragma unroll
    for (int off = 32; off > 0; off >>= 1)
        m = fmaxf(m, __shfl_xor(m, off, 64));
    const float qmax2 = m;

    const uint4 kv = ((const uint4*)Xksf16)[row];   // coalesced 16B/lane
    unsigned kd[8];
    kd[0] = dupL(kv.x); kd[1] = dupH(kv.x);
    kd[2] = dupL(kv.y); kd[3] = dupH(kv.y);
    kd[4] = dupL(kv.z); kd[5] = dupH(kv.z);
    kd[6] = dupL(kv.w); kd[7] = dupH(kv.w);
    float kn2 = 0.f;
    #pragma unroll
    for (int c = 0; c < 8; c++) {
        const float kf = (float)asV(kd[c]).x;
        kn2 = fmaf(kf, kf, kn2);
    }
    const float sinit = -sqrtf(kn2 * qmax2);  // s <= -sinit: p in (0,~1]
    const hv2 sinit2 = asV(pku(sinit, sinit));
    const hv2 one2   = asV(0x3C003C00u);
    hv2 l2 = asV(0u), acc[8];
    #pragma unroll
    for (int c = 0; c < 8; c++) acc[c] = asV(0u);

    // Pin pair base into a VGPR: compiler can no longer prove uniformity, so
    // QV reads become vector loads (runtime-uniform addr -> HW broadcast).
    int pbase = (chunk * 4 + wv) * ppw;
    asm volatile("" : "+v"(pbase));
    const uint4* QV4 = (const uint4*)QV + (size_t)pbase * 4;

    #pragma unroll 4
    for (int p = 0; p < ppw; p++) {
        const uint4 qp0 = QV4[p * 4 + 0];   // q2pair c0..3
        const uint4 qp1 = QV4[p * 4 + 1];   // q2pair c4..7
        const uint4 vp0 = QV4[p * 4 + 2];   // v2pair c0..3
        const uint4 vp1 = QV4[p * 4 + 3];   // v2pair c4..7
        hv2 s2 = sinit2;
        s2 = h2fma(asV(kd[0]), asV(qp0.x), s2);
        s2 = h2fma(asV(kd[1]), asV(qp0.y), s2);
        s2 = h2fma(asV(kd[2]), asV(qp0.z), s2);
        s2 = h2fma(asV(kd[3]), asV(qp0.w), s2);
        s2 = h2fma(asV(kd[4]), asV(qp1.x), s2);
        s2 = h2fma(asV(kd[5]), asV(qp1.y), s2);
        s2 = h2fma(asV(kd[6]), asV(qp1.z), s2);
        s2 = h2fma(asV(kd[7]), asV(qp1.w), s2);
        const float pa = __builtin_amdgcn_exp2f((float)s2.x);
        const float pb = __builtin_amdgcn_exp2f((float)s2.y);
        const hv2 ph = asV(pku(pa, pb));
        l2 = h2fma(ph, one2, l2);
        acc[0] = h2fma(ph, asV(vp0.x), acc[0]);
        acc[1] = h2fma(ph, asV(vp0.y), acc[1]);
        acc[2] = h2fma(ph, asV(vp0.z), acc[2]);
        acc[3] = h2fma(ph, asV(vp0.w), acc[3]);
        acc[4] = h2fma(ph, asV(vp1.x), acc[4]);
        acc[5] = h2fma(ph, asV(vp1.y), acc[5]);
        acc[6] = h2fma(ph, asV(vp1.z), acc[6]);
        acc[7] = h2fma(ph, asV(vp1.w), acc[7]);
    }

    // merge the block's 4 waves once via LDS (no atomics, no butterfly)
    #pragma unroll
    for (int c = 0; c < 8; c++)
        red[wv][lane][c] = (float)acc[c].x + (float)acc[c].y;
    red[wv][lane][8] = (float)l2.x + (float)l2.y;
    __syncthreads();
    for (int e = tid; e < 576; e += 256) {
        const int r = e / 9, c = e - r * 9;
        const float s = red[0][r][c] + red[1][r][c] + red[2][r][c] + red[3][r][c];
        part[((size_t)chunk * 8192 + rgrp * 64 + r) * 9 + c] = s;
    }
}

// 256 blocks x 32 rows: spread the latency-bound part-reduction over all CUs.
__global__ __launch_bounds__(256) void finish_kernel(
    const float* __restrict__ x,
    const float* __restrict__ Zw, const float* __restrict__ Zb,
    const float* __restrict__ part, float* __restrict__ out, int nch)
{
    __shared__ float Zs[32 * 9];
    __shared__ float zw_s[384];
    __shared__ float zb_s[48];
    const int tid = threadIdx.x;
    const int r0 = blockIdx.x * 32;

    for (int i = tid; i < 384; i += 256) zw_s[i] = Zw[i];
    if (tid < 48) zb_s[tid] = Zb[tid];

    if (tid < 32) {
        const int row = r0 + tid;
        float a[9];
        #pragma unroll
        for (int c = 0; c < 9; c++) a[c] = 0.f;
        for (int ch = 0; ch < nch; ch++) {
            const float* p = part + ((size_t)ch * 8192 + row) * 9;
            #pragma unroll
            for (int c = 0; c < 9; c++) a[c] += p[c];
        }
        const float inv = 1.0f / a[8];
        #pragma unroll
        for (int c = 0; c < 8; c++) Zs[tid * 9 + c] = a[c] * inv;
    }
    __syncthreads();

    for (int e = tid; e < 32 * 48; e += 256) {
        const int r = e / 48, c = e - r * 48;
        float o = x[r0 * 48 + e] + zb_s[c];
        #pragma unroll
        for (int k = 0; k < 8; k++) o = fmaf(Zs[r * 9 + k], zw_s[k * 48 + c], o);
        out[r0 * 48 + e] = o;
    }
}

extern "C" void kernel_launch(void* const* d_in, const int* in_sizes, int n_in,
                              void* d_out, int out_size, void* d_ws, size_t ws_size,
                              hipStream_t stream) {
    const float* x  = (const float*)d_in[0];
    const float* Kw = (const float*)d_in[1];
    const float* Kb = (const float*)d_in[2];
    const float* Qw = (const float*)d_in[3];
    const float* Qb = (const float*)d_in[4];
    const float* Vw = (const float*)d_in[5];
    const float* Vb = (const float*)d_in[6];
    const float* Zw = (const float*)d_in[7];
    const float* Zb = (const float*)d_in[8];
    float* out = (float*)d_out;

    float* ws = (float*)d_ws;
    unsigned* Xksf16 = (unsigned*)ws;
    unsigned* QV     = (unsigned*)(ws + QV_OFF);
    float* bmax      = ws + BMAX_OFF;
    float* part      = ws + PART_OFF;

    int nch = 16;
    const size_t avail = ws_size / 4;
    while (nch > 1 && (size_t)PART_OFF + (size_t)nch * 8192 * 9 > avail) nch >>= 1;
    const int ppw = 1024 / nch;   // j-pairs per wave (4096 pairs / (nch*4 waves))

    proj_kernel<<<256, 256, 0, stream>>>(x, Kw, Kb, Qw, Qb, Vw, Vb,
                                         Xksf16, QV, bmax);
    attn_kernel<<<128 * nch, 256, 0, stream>>>(Xksf16, QV, bmax, part, ppw);
    finish_kernel<<<256, 256, 0, stream>>>(x, Zw, Zb, part, out, nch);
}

// Round 2
// 111.016 us; speedup vs baseline: 1.2936x; 1.2936x over previous
//
#include <hip/hip_runtime.h>
#include <hip/hip_fp16.h>

// Ultimus: out = x + softmax((x@Kw+Kb)@(x@Qw+Qb)^T / sqrt(8)) @ (x@Vw+Vb) @ Zw + Zb
// N=8192, D_IN=48, D_ATTN=8, fp32 in/out.
//
// R13: attn data path v3. R11 (s_load per pair) = 40.4us: serialized on SMEM
// latency (out-of-order returns force lgkmcnt(0) drains). R12 (uniform vector
// loads) = 66.8us: VGPR=32 meant ~2 loads in flight -> raw L1/L2 latency per
// pair. R13 stages each block's 16KB QV slab into LDS with ONE bulk coalesced
// pass (4x global_load_dwordx4/thread, L2-resident), then the inner loop reads
// wave-uniform ds_read_b128: broadcast, conflict-free, compiler pipelines with
// fine-grained lgkmcnt(N). The red[] merge buffer aliases the slab (no LDS
// growth). Math is bit-identical to R11/R12.
//
//  - Bound-softmax (Cauchy-Schwarz row bound) => fixed per-row exponent
//    shift; partials over disjoint j-chunks combine by pure addition.
//  - QV pair-interleaved: dword c of pair p = half2(val[2p][c], val[2p+1][c])
//    so one pk_fma accumulates scores for both j's of the pair at once.
//
// ws layout (floats):
//   [0, 32768)      Xksf16[8192] 8 f16/row (k * log2e/sqrt(8)), uint4/row
//   [32768, 98304)  QV per pair p: 16 dwords = q2pair[8] | v2pair[8]
//   [98304, 98560)  bmax[256] per-proj-block max ||q||^2 (plain store)
//   [98560, ...)    part[nch][8192][9] f32 partials: acc[0:8], l at [8]

#define QV_OFF   32768
#define BMAX_OFF 98304
#define PART_OFF 98560

typedef _Float16 hv2 __attribute__((ext_vector_type(2)));
union HVU { unsigned u; hv2 v; };

static __device__ __forceinline__ unsigned pku(float a, float b) {
    auto t = __builtin_amdgcn_cvt_pkrtz(a, b);
    union { decltype(t) x; unsigned u; } c; c.x = t; return c.u;
}
static __device__ __forceinline__ hv2 asV(unsigned u) { HVU t; t.u = u; return t.v; }
static __device__ __forceinline__ hv2 h2fma(hv2 a, hv2 b, hv2 c) {
#if __has_builtin(__builtin_elementwise_fma)
    return __builtin_elementwise_fma(a, b, c);
#else
    union { hv2 v; __half2 h; } A, B, C, D;
    A.v = a; B.v = b; C.v = c;
    D.h = __hfma2(A.h, B.h, C.h);
    return D.v;
#endif
}
static __device__ __forceinline__ unsigned dupL(unsigned u) {
    const unsigned lo = u & 0xFFFFu; return lo | (lo << 16);
}
static __device__ __forceinline__ unsigned dupH(unsigned u) {
    const unsigned hi = u >> 16; return hi | (hi << 16);
}

__global__ __launch_bounds__(256) void proj_kernel(
    const float* __restrict__ x,
    const float* __restrict__ Kw, const float* __restrict__ Kb,
    const float* __restrict__ Qw, const float* __restrict__ Qb,
    const float* __restrict__ Vw, const float* __restrict__ Vb,
    unsigned* __restrict__ Xksf16, unsigned* __restrict__ QV,
    float* __restrict__ bmax)
{
    __shared__ float xs[32 * 49];     // +1 pad
    __shared__ float wAll[3 * 388];   // stride 388 (mod 32 = 4) spreads 3 mats
    __shared__ float bs[24];
    __shared__ float outv[32][25];    // 24 cols + pad
    const int tid = threadIdx.x;
    const int r0 = blockIdx.x * 32;

    for (int i = tid; i < 1536; i += 256) {
        int r = i / 48, c = i - r * 48;
        xs[r * 49 + c] = x[r0 * 48 + i];
    }
    for (int i = tid; i < 384; i += 256) {
        wAll[i]       = Kw[i];
        wAll[388 + i] = Qw[i];
        wAll[776 + i] = Vw[i];
    }
    if (tid < 8)       bs[tid] = Kb[tid];
    else if (tid < 16) bs[tid] = Qb[tid - 8];
    else if (tid < 24) bs[tid] = Vb[tid - 16];
    __syncthreads();

    const int rl = tid >> 3;
    const int g  = tid & 7;
    const int c0 = 3 * g;
    const float* xr = &xs[rl * 49];
    const float* w0 = &wAll[((c0 + 0) >> 3) * 388 + ((c0 + 0) & 7)];
    const float* w1 = &wAll[((c0 + 1) >> 3) * 388 + ((c0 + 1) & 7)];
    const float* w2 = &wAll[((c0 + 2) >> 3) * 388 + ((c0 + 2) & 7)];
    float a0 = bs[c0], a1 = bs[c0 + 1], a2 = bs[c0 + 2];
    #pragma unroll
    for (int k = 0; k < 48; k++) {
        const float xv = xr[k];
        a0 = fmaf(xv, w0[k * 8], a0);
        a1 = fmaf(xv, w1[k * 8], a1);
        a2 = fmaf(xv, w2[k * 8], a2);
    }
    outv[rl][c0] = a0; outv[rl][c0 + 1] = a1; outv[rl][c0 + 2] = a2;
    __syncthreads();

    // QV pair-interleaved: pair p (16/block), col c (8), m: 0=q, 1=v
    {
        const int p = tid >> 4;
        const int c = (tid >> 1) & 7;
        const int m = tid & 1;
        const int col = (m ? 16 : 8) + c;
        QV[(blockIdx.x * 16 + p) * 16 + m * 8 + c] =
            pku(outv[2 * p][col], outv[2 * p + 1][col]);
    }
    const float kscale = 0.51008732149f;  // (1/sqrt(8)) * log2(e)
    if (tid < 32) {                       // K rows, f16 packed, pre-scaled
        uint4 o;
        o.x = pku(outv[tid][0] * kscale, outv[tid][1] * kscale);
        o.y = pku(outv[tid][2] * kscale, outv[tid][3] * kscale);
        o.z = pku(outv[tid][4] * kscale, outv[tid][5] * kscale);
        o.w = pku(outv[tid][6] * kscale, outv[tid][7] * kscale);
        ((uint4*)Xksf16)[r0 + tid] = o;
    }
    if (tid >= 192 && tid < 224) {        // block-max ||q||^2 (fp32)
        const int r = tid - 192;
        float n2 = 0.f;
        #pragma unroll
        for (int c = 0; c < 8; c++) n2 = fmaf(outv[r][8 + c], outv[r][8 + c], n2);
        #pragma unroll
        for (int off = 16; off > 0; off >>= 1)
            n2 = fmaxf(n2, __shfl_xor(n2, off, 64));
        if (r == 0) bmax[blockIdx.x] = n2;
    }
}

// grid = 128 row-groups (64 rows; row = lane) x nch j-chunks.
// Wave w handles pairs [(chunk*4 + w)*ppw, +ppw) in tiles of 64 pairs.
// Each tile: block cooperatively stages 4 waves x 64 pairs x 64B = 16KB of
// QV into LDS (coalesced dwordx4), then the pair loop reads wave-uniform
// ds_read_b128 (broadcast, conflict-free, lgkmcnt-pipelined).
__global__ __launch_bounds__(256) void attn_kernel(
    const unsigned* __restrict__ Xksf16, const unsigned* __restrict__ QV,
    const float* __restrict__ bmax,
    float* __restrict__ part, int ppw)
{
    __shared__ uint4 slab[1024];       // 16 KB; red[] aliases this after loop
    const int tid  = threadIdx.x;
    const int lane = tid & 63;
    const int wv   = tid >> 6;
    const int rgrp  = blockIdx.x & 127;
    const int chunk = blockIdx.x >> 7;
    const int row   = rgrp * 64 + lane;

    // qmax2 = max over 256 per-proj-block maxima
    float m = fmaxf(fmaxf(bmax[lane], bmax[64 + lane]),
                    fmaxf(bmax[128 + lane], bmax[192 + lane]));
    #pragma unroll
    for (int off = 32; off > 0; off >>= 1)
        m = fmaxf(m, __shfl_xor(m, off, 64));
    const float qmax2 = m;

    const uint4 kv = ((const uint4*)Xksf16)[row];   // coalesced 16B/lane
    unsigned kd[8];
    kd[0] = dupL(kv.x); kd[1] = dupH(kv.x);
    kd[2] = dupL(kv.y); kd[3] = dupH(kv.y);
    kd[4] = dupL(kv.z); kd[5] = dupH(kv.z);
    kd[6] = dupL(kv.w); kd[7] = dupH(kv.w);
    float kn2 = 0.f;
    #pragma unroll
    for (int c = 0; c < 8; c++) {
        const float kf = (float)asV(kd[c]).x;
        kn2 = fmaf(kf, kf, kn2);
    }
    const float sinit = -sqrtf(kn2 * qmax2);  // s <= -sinit: p in (0,~1]
    const hv2 sinit2 = asV(pku(sinit, sinit));
    const hv2 one2   = asV(0x3C003C00u);
    hv2 l2 = asV(0u), acc[8];
    #pragma unroll
    for (int c = 0; c < 8; c++) acc[c] = asV(0u);

    const uint4* QV4 = (const uint4*)QV;
    const int nt = ppw >> 6;           // ppw is always a multiple of 64

    for (int t = 0; t < nt; ++t) {
        // stage: wave w's 64-pair tile -> slab[w*256 .. w*256+256)
        // global uint4 index for (w, j): ((chunk*4+w)*ppw + t*64)*4 + j
        for (int i = tid; i < 1024; i += 256) {
            const int w = i >> 8;
            const int j = i & 255;
            slab[i] = QV4[(size_t)((((chunk * 4 + w) * ppw + (t << 6)) << 2) + j)];
        }
        __syncthreads();

        const uint4* sw = &slab[wv << 8];
        #pragma unroll 2
        for (int p = 0; p < 64; ++p) {
            const uint4 qp0 = sw[p * 4 + 0];   // q2pair c0..3
            const uint4 qp1 = sw[p * 4 + 1];   // q2pair c4..7
            const uint4 vp0 = sw[p * 4 + 2];   // v2pair c0..3
            const uint4 vp1 = sw[p * 4 + 3];   // v2pair c4..7
            hv2 s2 = sinit2;
            s2 = h2fma(asV(kd[0]), asV(qp0.x), s2);
            s2 = h2fma(asV(kd[1]), asV(qp0.y), s2);
            s2 = h2fma(asV(kd[2]), asV(qp0.z), s2);
            s2 = h2fma(asV(kd[3]), asV(qp0.w), s2);
            s2 = h2fma(asV(kd[4]), asV(qp1.x), s2);
            s2 = h2fma(asV(kd[5]), asV(qp1.y), s2);
            s2 = h2fma(asV(kd[6]), asV(qp1.z), s2);
            s2 = h2fma(asV(kd[7]), asV(qp1.w), s2);
            const float pa = __builtin_amdgcn_exp2f((float)s2.x);
            const float pb = __builtin_amdgcn_exp2f((float)s2.y);
            const hv2 ph = asV(pku(pa, pb));
            l2 = h2fma(ph, one2, l2);
            acc[0] = h2fma(ph, asV(vp0.x), acc[0]);
            acc[1] = h2fma(ph, asV(vp0.y), acc[1]);
            acc[2] = h2fma(ph, asV(vp0.z), acc[2]);
            acc[3] = h2fma(ph, asV(vp0.w), acc[3]);
            acc[4] = h2fma(ph, asV(vp1.x), acc[4]);
            acc[5] = h2fma(ph, asV(vp1.y), acc[5]);
            acc[6] = h2fma(ph, asV(vp1.z), acc[6]);
            acc[7] = h2fma(ph, asV(vp1.w), acc[7]);
        }
        __syncthreads();   // all waves done reading slab before reuse
    }

    // merge the block's 4 waves once via LDS (red aliases the slab: 13312B)
    float (*red)[64][13] = reinterpret_cast<float (*)[64][13]>(slab);
    #pragma unroll
    for (int c = 0; c < 8; c++)
        red[wv][lane][c] = (float)acc[c].x + (float)acc[c].y;
    red[wv][lane][8] = (float)l2.x + (float)l2.y;
    __syncthreads();
    for (int e = tid; e < 576; e += 256) {
        const int r = e / 9, c = e - r * 9;
        const float s = red[0][r][c] + red[1][r][c] + red[2][r][c] + red[3][r][c];
        part[((size_t)chunk * 8192 + rgrp * 64 + r) * 9 + c] = s;
    }
}

// 256 blocks x 32 rows: spread the latency-bound part-reduction over all CUs.
__global__ __launch_bounds__(256) void finish_kernel(
    const float* __restrict__ x,
    const float* __restrict__ Zw, const float* __restrict__ Zb,
    const float* __restrict__ part, float* __restrict__ out, int nch)
{
    __shared__ float Zs[32 * 9];
    __shared__ float zw_s[384];
    __shared__ float zb_s[48];
    const int tid = threadIdx.x;
    const int r0 = blockIdx.x * 32;

    for (int i = tid; i < 384; i += 256) zw_s[i] = Zw[i];
    if (tid < 48) zb_s[tid] = Zb[tid];

    if (tid < 32) {
        const int row = r0 + tid;
        float a[9];
        #pragma unroll
        for (int c = 0; c < 9; c++) a[c] = 0.f;
        for (int ch = 0; ch < nch; ch++) {
            const float* p = part + ((size_t)ch * 8192 + row) * 9;
            #pragma unroll
            for (int c = 0; c < 9; c++) a[c] += p[c];
        }
        const float inv = 1.0f / a[8];
        #pragma unroll
        for (int c = 0; c < 8; c++) Zs[tid * 9 + c] = a[c] * inv;
    }
    __syncthreads();

    for (int e = tid; e < 32 * 48; e += 256) {
        const int r = e / 48, c = e - r * 48;
        float o = x[r0 * 48 + e] + zb_s[c];
        #pragma unroll
        for (int k = 0; k < 8; k++) o = fmaf(Zs[r * 9 + k], zw_s[k * 48 + c], o);
        out[r0 * 48 + e] = o;
    }
}

extern "C" void kernel_launch(void* const* d_in, const int* in_sizes, int n_in,
                              void* d_out, int out_size, void* d_ws, size_t ws_size,
                              hipStream_t stream) {
    const float* x  = (const float*)d_in[0];
    const float* Kw = (const float*)d_in[1];
    const float* Kb = (const float*)d_in[2];
    const float* Qw = (const float*)d_in[3];
    const float* Qb = (const float*)d_in[4];
    const float* Vw = (const float*)d_in[5];
    const float* Vb = (const float*)d_in[6];
    const float* Zw = (const float*)d_in[7];
    const float* Zb = (const float*)d_in[8];
    float* out = (float*)d_out;

    float* ws = (float*)d_ws;
    unsigned* Xksf16 = (unsigned*)ws;
    unsigned* QV     = (unsigned*)(ws + QV_OFF);
    float* bmax      = ws + BMAX_OFF;
    float* part      = ws + PART_OFF;

    int nch = 16;
    const size_t avail = ws_size / 4;
    while (nch > 1 && (size_t)PART_OFF + (size_t)nch * 8192 * 9 > avail) nch >>= 1;
    const int ppw = 1024 / nch;   // j-pairs per wave (4096 pairs / (nch*4 waves))

    proj_kernel<<<256, 256, 0, stream>>>(x, Kw, Kb, Qw, Qb, Vw, Vb,
                                         Xksf16, QV, bmax);
    attn_kernel<<<128 * nch, 256, 0, stream>>>(Xksf16, QV, bmax, part, ppw);
    finish_kernel<<<256, 256, 0, stream>>>(x, Zw, Zb, part, out, nch);
}